// Round 5
// baseline (184.514 us; speedup 1.0000x reference)
//
#include <hip/hip_runtime.h>

// FD_discretizer on fixed 1024x1024 grid, Ex=Ey=1026 extended grid.
// Round 5: fast path computes a 2x2 output patch per thread (256-thr blocks,
// tile = 8 rows x 128 cols). Center-row face quantities are shared between
// the two output rows. Non-temporal output stores. Edge frame handled by 24
// dedicated slow blocks placed first in the grid.

#define NXC 1024               // NX == NY
#define EXC 1026               // Ex == Ey
#define NN  (NXC*NXC)

enum { T_NORMAL=0, T_INFLOW=4, T_OUTFLOW=5, T_WALL=6, T_PRESS=7 };

struct V3 { float u,v,p; };

__device__ __forceinline__ int ntype(int io,int jo){
  if (io==NXC-1) return T_OUTFLOW;
  if (io==0)     return T_INFLOW;
  if (jo==0 || jo==NXC-1) return T_WALL;
  return T_NORMAL;
}

// BC-enforced extended field value at extended coords (je,ie) in [0,1025]^2.
template<bool NEWF>
__device__ __forceinline__ V3 ext_at(int je,int ie,
    const float* __restrict__ uvp,
    const float* __restrict__ node_y)
{
  V3 r;
  const bool bl=(ie==0), br=(ie==EXC-1), bb=(je==0), bt=(je==EXC-1);
  const bool onx = bl||br, ony = bb||bt;
  const bool ghost = (onx && !ony) || (ony && !onx);   // ring minus corners
  if (!ghost){
    int io = ie-1; io = io<0?0:(io>NXC-1?NXC-1:io);
    int jo = je-1; jo = jo<0?0:(jo>NXC-1?NXC-1:jo);
    int m3 = 3*(jo*NXC+io);
    r.u = uvp[m3]; r.v = uvp[m3+1]; r.p = uvp[m3+2];
    if (NEWF && je==EXC/2 && ie==EXC/2) r.p = 0.f;     // PRESS_POINT
    return r;
  }
  int dje=0, die=0, gt;
  if (bl)      { die= 1; gt=T_INFLOW;  }
  else if (br) { die=-1; gt=T_OUTFLOW; }
  else if (bb) { dje= 1; gt=T_WALL;    }
  else         { dje=-1; gt=T_WALL;    }
  int io1 = ie+die-1, jo1 = je+dje-1;
  int m1 = 3*(jo1*NXC+io1);
  int m2 = 3*((jo1+dje)*NXC + (io1+die));
  float u2=uvp[m2], v2=uvp[m2+1], p2=uvp[m2+2];
  int nt1 = ntype(io1,jo1);
  if (gt==T_OUTFLOW){
    float p1 = (nt1==T_OUTFLOW) ? 0.f : uvp[m1+2];
    r.u=u2; r.v=v2; r.p = 2.f*p1 - p2;
  } else {
    float du,dv;
    if (nt1==T_INFLOW || nt1==T_WALL){ du=node_y[m1]; dv=node_y[m1+1]; }
    else                             { du=uvp[m1];    dv=uvp[m1+1];    }
    r.u = 2.f*du - u2; r.v = 2.f*dv - v2; r.p = p2;
  }
  return r;
}

// full slow-path computation for one output node (round-2-verified)
__device__ void process_slow(int io,int jo,
    const float* __restrict__ uvp, const float* __restrict__ uvo,
    const float* __restrict__ ndy, const float* __restrict__ ebm,
    float dt,float uc,float cc,float convc,float pc,float dc,float relax,
    float* __restrict__ out)
{
  const int o = jo*NXC + io;
  const int ie0 = io+1, je0 = jo+1;
  V3 C  = ext_at<true >(je0,  ie0,  uvp, ndy);
  V3 W  = ext_at<true >(je0,  ie0-1,uvp, ndy);
  V3 E  = ext_at<true >(je0,  ie0+1,uvp, ndy);
  V3 S  = ext_at<true >(je0-1,ie0,  uvp, ndy);
  V3 Nn = ext_at<true >(je0+1,ie0,  uvp, ndy);
  V3 SW = ext_at<true >(je0-1,ie0-1,uvp, ndy);
  V3 SE = ext_at<true >(je0-1,ie0+1,uvp, ndy);
  V3 NW = ext_at<true >(je0+1,ie0-1,uvp, ndy);
  V3 NE = ext_at<true >(je0+1,ie0+1,uvp, ndy);
  V3 Co = ext_at<false>(je0,  ie0,  uvo, ndy);
  V3 Wo = ext_at<false>(je0,  ie0-1,uvo, ndy);
  V3 Eo = ext_at<false>(je0,  ie0+1,uvo, ndy);
  V3 So = ext_at<false>(je0-1,ie0,  uvo, ndy);
  V3 No = ext_at<false>(je0+1,ie0,  uvo, ndy);

  const int eC = je0*EXC+ie0;
  const int eW = eC-1, eE = eC+1, eS = eC-EXC, eN = eC+EXC;
  float dxxC=ebm[5*eC+0], dxyC=ebm[5*eC+1], dexC=ebm[5*eC+2],
        deyC=ebm[5*eC+3], JmC=ebm[5*eC+4];
  float dxxW=ebm[5*eW+0], dxyW=ebm[5*eW+1], JmW=ebm[5*eW+4];
  float dxxE=ebm[5*eE+0], dxyE=ebm[5*eE+1], JmE=ebm[5*eE+4];
  float dexS=ebm[5*eS+2], deyS=ebm[5*eS+3], JmS=ebm[5*eS+4];
  float dexN=ebm[5*eN+2], deyN=ebm[5*eN+3], JmN=ebm[5*eN+4];
  const float rC=1.f/JmC, rW=1.f/JmW, rE=1.f/JmE, rS=1.f/JmS, rN=1.f/JmN;

  float UC=(C.u*dxxC + C.v*dxyC)*rC, UW=(W.u*dxxW + W.v*dxyW)*rW, UE=(E.u*dxxE + E.v*dxyE)*rE;
  float VC=(C.u*dexC + C.v*deyC)*rC, VS=(S.u*dexS + S.v*deyS)*rS, VN=(Nn.u*dexN + Nn.v*deyN)*rN;
  float UCo=(Co.u*dxxC + Co.v*dxyC)*rC, UWo=(Wo.u*dxxW + Wo.v*dxyW)*rW, UEo=(Eo.u*dxxE + Eo.v*dxyE)*rE;
  float VCo=(Co.u*dexC + Co.v*deyC)*rC, VSo=(So.u*dexS + So.v*deyS)*rS, VNo=(No.u*dexN + No.v*deyN)*rN;

  float Ufl =0.5f*(UW +UC ), Ufr =0.5f*(UC +UE );
  float Vfd =0.5f*(VS +VC ), Vfu =0.5f*(VC +VN );
  float Uflo=0.5f*(UWo+UCo), Ufro=0.5f*(UCo+UEo);
  float Vfdo=0.5f*(VSo+VCo), Vfuo=0.5f*(VCo+VNo);

  const float loss = (Ufr - Ufl + Vfu - Vfd) * cc;

  float cnu = 0.5f*(C.u+E.u)*Ufr - 0.5f*(W.u+C.u)*Ufl + 0.5f*(C.u+Nn.u)*Vfu - 0.5f*(S.u+C.u)*Vfd;
  float cnv = 0.5f*(C.v+E.v)*Ufr - 0.5f*(W.v+C.v)*Ufl + 0.5f*(C.v+Nn.v)*Vfu - 0.5f*(S.v+C.v)*Vfd;
  float cou = 0.5f*(Co.u+Eo.u)*Ufro - 0.5f*(Wo.u+Co.u)*Uflo + 0.5f*(Co.u+No.u)*Vfuo - 0.5f*(So.u+Co.u)*Vfdo;
  float cov = 0.5f*(Co.v+Eo.v)*Ufro - 0.5f*(Wo.v+Co.v)*Uflo + 0.5f*(Co.v+No.v)*Vfuo - 0.5f*(So.v+Co.v)*Vfdo;
  const float convu = relax*cou + (1.f-relax)*cnu;
  const float convv = relax*cov + (1.f-relax)*cnv;

  float a11C=(dxxC*dxxC+dxyC*dxyC)*rC, a11W=(dxxW*dxxW+dxyW*dxyW)*rW, a11E=(dxxE*dxxE+dxyE*dxyE)*rE;
  float a22C=(dexC*dexC+deyC*deyC)*rC, a22S=(dexS*dexS+deyS*deyS)*rS, a22N=(dexN*dexN+deyN*deyN)*rN;
  float du = 0.5f*(a11C+a11E)*(E.u -C.u) - 0.5f*(a11W+a11C)*(C.u-W.u)
           + 0.5f*(a22C+a22N)*(Nn.u-C.u) - 0.5f*(a22S+a22C)*(C.u-S.u);
  float dv = 0.5f*(a11C+a11E)*(E.v -C.v) - 0.5f*(a11W+a11C)*(C.v-W.v)
           + 0.5f*(a22C+a22N)*(Nn.v-C.v) - 0.5f*(a22S+a22C)*(C.v-S.v);

  float pqW=W.p*rW, pqE=E.p*rE, pqS=S.p*rS, pqN=Nn.p*rN;
  const float gPx = 0.5f*(pqE*dxxE - pqW*dxxW) + 0.5f*(pqN*dexN - pqS*dexS);
  const float gPy = 0.5f*(pqN*deyN - pqS*deyS) + 0.5f*(pqE*dxyE - pqW*dxyW);

  const float rdt = 1.f/dt;
  const float unst_u = (C.u - Co.u)*rdt*rC;
  const float unst_v = (C.v - Co.v)*rdt*rC;

  const float momu = uc*unst_u + convc*convu + pc*gPx - dc*du;
  const float momv = uc*unst_v + convc*convv + pc*gPy - dc*dv;

  const float visu = (SW.u+SE.u+NW.u+NE.u + 2.f*(S.u+W.u+E.u+Nn.u) + 4.f*C.u)*0.0625f;
  const float visv = (SW.v+SE.v+NW.v+NE.v + 2.f*(S.v+W.v+E.v+Nn.v) + 4.f*C.v)*0.0625f;
  const float visp = (SW.p+SE.p+NW.p+NE.p + 2.f*(S.p+W.p+E.p+Nn.p) + 4.f*C.p)*0.0625f;

  out[o]        = loss;
  out[NN + o]   = momu;
  out[2*NN + o] = momv;
  const int vb = 3*NN + 3*o;
  out[vb]   = visu;
  out[vb+1] = visv;
  out[vb+2] = visp;
}

// ---- fast-path helpers ------------------------------------------------------

struct Face { float V[2],Vo[2],a22[2],pex[2],pey[2]; };
struct Ctr  { float U[4],Uo[4],a11[4],pqx[4],pqy[4],rJc[2]; Face f; };

// center row: n,q = 12 floats (patch cols 0..3), m = 20 floats (metrics cols 0..3)
__device__ __forceinline__ Ctr mkCtr(const float* __restrict__ n,
                                     const float* __restrict__ q,
                                     const float* __restrict__ m){
  Ctr c; float rJ[4];
  #pragma unroll
  for(int k=0;k<4;k++){
    const float dxx=m[5*k], dxy=m[5*k+1];
    rJ[k]=1.f/m[5*k+4];
    c.U[k] =(n[3*k]*dxx + n[3*k+1]*dxy)*rJ[k];
    c.Uo[k]=(q[3*k]*dxx + q[3*k+1]*dxy)*rJ[k];
    c.a11[k]=(dxx*dxx+dxy*dxy)*rJ[k];
    const float pq=n[3*k+2]*rJ[k];
    c.pqx[k]=pq*dxx; c.pqy[k]=pq*dxy;
  }
  #pragma unroll
  for(int i=0;i<2;i++){
    const int k=1+i;
    const float dex=m[5*k+2], dey=m[5*k+3];
    c.rJc[i]=rJ[k];
    c.f.V[i] =(n[3*k]*dex + n[3*k+1]*dey)*rJ[k];
    c.f.Vo[i]=(q[3*k]*dex + q[3*k+1]*dey)*rJ[k];
    c.f.a22[i]=(dex*dex+dey*dey)*rJ[k];
    const float pq=n[3*k+2]*rJ[k];
    c.f.pex[i]=pq*dex; c.f.pey[i]=pq*dey;
  }
  return c;
}

// S/N face row: n = 12 floats (patch cols 0..3), q = 6 floats (cols 1..2),
// m = 10 floats (metric cols 1..2)
__device__ __forceinline__ Face mkFace(const float* __restrict__ n,
                                       const float* __restrict__ q,
                                       const float* __restrict__ m){
  Face f;
  #pragma unroll
  for(int i=0;i<2;i++){
    const float dex=m[5*i+2], dey=m[5*i+3], r=1.f/m[5*i+4];
    const int mm=1+i;
    f.V[i] =(n[3*mm]*dex + n[3*mm+1]*dey)*r;
    f.Vo[i]=(q[3*i]*dex + q[3*i+1]*dey)*r;
    f.a22[i]=(dex*dex+dey*dey)*r;
    const float pq=n[3*mm+2]*r;
    f.pex[i]=pq*dex; f.pey[i]=pq*dey;
  }
  return f;
}

__device__ __forceinline__ void emitRow(
  const float* __restrict__ nS,const float* __restrict__ nC,const float* __restrict__ nN,
  const float* __restrict__ qC,
  float uoS0,float voS0,float uoS1,float voS1,
  float uoN0,float voN0,float uoN1,float voN1,
  const Ctr& ct, const Face& fS, const Face& fN,
  float cc,float uc,float convc,float pc,float dc,float relax,float rdt,
  int o, float* __restrict__ out)
{
  float Lo[2],Mu[2],Mv[2],Vu[2],Vv[2],Vp[2];
  #pragma unroll
  for(int i=0;i<2;i++){
    const int m=1+i;
    const float Ufl =0.5f*(ct.U[m-1]+ct.U[m]),   Ufr =0.5f*(ct.U[m]+ct.U[m+1]);
    const float Uflo=0.5f*(ct.Uo[m-1]+ct.Uo[m]), Ufro=0.5f*(ct.Uo[m]+ct.Uo[m+1]);
    const float Vfd =0.5f*(fS.V[i]+ct.f.V[i]),   Vfu =0.5f*(ct.f.V[i]+fN.V[i]);
    const float Vfdo=0.5f*(fS.Vo[i]+ct.f.Vo[i]), Vfuo=0.5f*(ct.f.Vo[i]+fN.Vo[i]);

    Lo[i]=(Ufr-Ufl+Vfu-Vfd)*cc;

    const float u_c=nC[3*m],   v_c=nC[3*m+1];
    const float uW =nC[3*m-3], vW =nC[3*m-2];
    const float uE =nC[3*m+3], vE =nC[3*m+4];
    const float uS =nS[3*m],   vS =nS[3*m+1];
    const float uN =nN[3*m],   vN =nN[3*m+1];

    const float cnu=0.5f*(u_c+uE)*Ufr-0.5f*(uW+u_c)*Ufl+0.5f*(u_c+uN)*Vfu-0.5f*(uS+u_c)*Vfd;
    const float cnv=0.5f*(v_c+vE)*Ufr-0.5f*(vW+v_c)*Ufl+0.5f*(v_c+vN)*Vfu-0.5f*(vS+v_c)*Vfd;

    const float uoc=qC[3*m],   voc=qC[3*m+1];
    const float uoW=qC[3*m-3], voW=qC[3*m-2];
    const float uoE=qC[3*m+3], voE=qC[3*m+4];
    const float uoS=i?uoS1:uoS0, voS=i?voS1:voS0;
    const float uoN=i?uoN1:uoN0, voN=i?voN1:voN0;

    const float cou=0.5f*(uoc+uoE)*Ufro-0.5f*(uoW+uoc)*Uflo+0.5f*(uoc+uoN)*Vfuo-0.5f*(uoS+uoc)*Vfdo;
    const float cov=0.5f*(voc+voE)*Ufro-0.5f*(voW+voc)*Uflo+0.5f*(voc+voN)*Vfuo-0.5f*(voS+voc)*Vfdo;

    const float convu=relax*cou+(1.f-relax)*cnu;
    const float convv=relax*cov+(1.f-relax)*cnv;

    const float du=0.5f*(ct.a11[m]+ct.a11[m+1])*(uE-u_c)-0.5f*(ct.a11[m-1]+ct.a11[m])*(u_c-uW)
                  +0.5f*(ct.f.a22[i]+fN.a22[i])*(uN-u_c)-0.5f*(fS.a22[i]+ct.f.a22[i])*(u_c-uS);
    const float dv=0.5f*(ct.a11[m]+ct.a11[m+1])*(vE-v_c)-0.5f*(ct.a11[m-1]+ct.a11[m])*(v_c-vW)
                  +0.5f*(ct.f.a22[i]+fN.a22[i])*(vN-v_c)-0.5f*(fS.a22[i]+ct.f.a22[i])*(v_c-vS);

    const float gPx=0.5f*(ct.pqx[m+1]-ct.pqx[m-1])+0.5f*(fN.pex[i]-fS.pex[i]);
    const float gPy=0.5f*(fN.pey[i]-fS.pey[i])+0.5f*(ct.pqy[m+1]-ct.pqy[m-1]);

    const float unst_u=(u_c-uoc)*rdt*ct.rJc[i];
    const float unst_v=(v_c-voc)*rdt*ct.rJc[i];

    Mu[i]=uc*unst_u+convc*convu+pc*gPx-dc*du;
    Mv[i]=uc*unst_v+convc*convv+pc*gPy-dc*dv;

    Vu[i]=(nS[3*m-3]+2.f*nS[3*m]+nS[3*m+3]
      +2.f*(nC[3*m-3]+2.f*nC[3*m]+nC[3*m+3])
          + nN[3*m-3]+2.f*nN[3*m]+nN[3*m+3])*0.0625f;
    Vv[i]=(nS[3*m-2]+2.f*nS[3*m+1]+nS[3*m+4]
      +2.f*(nC[3*m-2]+2.f*nC[3*m+1]+nC[3*m+4])
          + nN[3*m-2]+2.f*nN[3*m+1]+nN[3*m+4])*0.0625f;
    Vp[i]=(nS[3*m-1]+2.f*nS[3*m+2]+nS[3*m+5]
      +2.f*(nC[3*m-1]+2.f*nC[3*m+2]+nC[3*m+5])
          + nN[3*m-1]+2.f*nN[3*m+2]+nN[3*m+5])*0.0625f;
  }
  __builtin_nontemporal_store(Lo[0], &out[o]);
  __builtin_nontemporal_store(Lo[1], &out[o+1]);
  __builtin_nontemporal_store(Mu[0], &out[NN+o]);
  __builtin_nontemporal_store(Mu[1], &out[NN+o+1]);
  __builtin_nontemporal_store(Mv[0], &out[2*NN+o]);
  __builtin_nontemporal_store(Mv[1], &out[2*NN+o+1]);
  const int vb=3*NN+3*o;
  __builtin_nontemporal_store(Vu[0], &out[vb]);
  __builtin_nontemporal_store(Vv[0], &out[vb+1]);
  __builtin_nontemporal_store(Vp[0], &out[vb+2]);
  __builtin_nontemporal_store(Vu[1], &out[vb+3]);
  __builtin_nontemporal_store(Vv[1], &out[vb+4]);
  __builtin_nontemporal_store(Vp[1], &out[vb+5]);
}

#define NEDGE_BLK 24

extern "C" __global__ void __launch_bounds__(256)
fd_kernel(const float* __restrict__ uvp,     // original_uv  n x 3
          const float* __restrict__ uvo,     // uv_old       n x 3
          const float* __restrict__ ndy,     // node_y       n x 3
          const float* __restrict__ ebm,     // ext metrics  n_ext x 5
          const float* __restrict__ dtg,     // dt           1
          const float* __restrict__ th,      // pde_theta    5
          const float* __restrict__ rl,      // relaxation   1
          float* __restrict__ out)
{
  const int bid = blockIdx.x;
  const int tid = threadIdx.x;

  const float dt   = dtg[0];
  const float uc   = th[0], cc = th[1], convc = th[2], pc = th[3], dc = th[4];
  const float relax= rl[0];
  const float rdt  = 1.f/dt;

  if (bid < NEDGE_BLK){
    // boundary frame: jo in {0,1023} all io, plus io in {0,1,1022,1023}
    // for jo in [1,1022]. 6136 nodes, 1 node/thread.
    const int t = bid*256 + tid;
    if (t >= 6136) return;
    int io, jo;
    if (t < 2048){ jo = (t < 1024) ? 0 : 1023; io = t & 1023; }
    else { int u = t - 2048; jo = 1 + (u >> 2); int c = u & 3; io = (c < 2) ? c : 1020 + c; }
    process_slow(io, jo, uvp,uvo,ndy,ebm, dt,uc,cc,convc,pc,dc,relax, out);
    return;
  }

  // -------- fast path: 2x2 outputs/thread; tile = 8 rows x 128 cols --------
  const int b  = bid - NEDGE_BLK;
  const int ct_ = b & 7, rt = b >> 3;        // ct_ -> fixed XCD column strip
  const int tx = tid & 63, ty = tid >> 6;
  const int x0 = 2 + ct_*128 + 2*tx;         // output cols x0, x0+1
  if (x0 > 1020) return;
  int jo0 = 1 + rt*8 + ty*2;                 // output rows jo0, jo0+1
  if (jo0 > 1021) jo0 = 1021;                // clamp: duplicate-write same values

  const int jm=jo0-1, j0=jo0, j1=jo0+1, jp=jo0+2;

  // new field: 4 rows x patch cols 0..3 (interior cols x0-1 .. x0+2)
  float nA[12], nB[12], nC_[12], nD[12];
  {
    const float* a = uvp + 3*(jm*NXC + x0-1);
    const float* b1= uvp + 3*(j0*NXC + x0-1);
    const float* c = uvp + 3*(j1*NXC + x0-1);
    const float* d = uvp + 3*(jp*NXC + x0-1);
    #pragma unroll
    for (int k=0;k<12;k++){ nA[k]=a[k]; nB[k]=b1[k]; nC_[k]=c[k]; nD[k]=d[k]; }
  }
  // old field: outer rows only cols x0..x0+1
  float qA[6], qB[12], qC2[12], qD[6];
  {
    const float* a = uvo + 3*(jm*NXC + x0);
    const float* b1= uvo + 3*(j0*NXC + x0-1);
    const float* c = uvo + 3*(j1*NXC + x0-1);
    const float* d = uvo + 3*(jp*NXC + x0);
    #pragma unroll
    for (int k=0;k<6;k++){ qA[k]=a[k]; qD[k]=d[k]; }
    #pragma unroll
    for (int k=0;k<12;k++){ qB[k]=b1[k]; qC2[k]=c[k]; }
  }
  // metrics: ext rows jo0..jo0+3; S/N rows only metric cols 1..2
  float m0[10], m1[20], m2[20], m3[10];
  {
    const float* a = ebm + 5*((jo0  )*EXC + x0+1);
    const float* b1= ebm + 5*((jo0+1)*EXC + x0);
    const float* c = ebm + 5*((jo0+2)*EXC + x0);
    const float* d = ebm + 5*((jo0+3)*EXC + x0+1);
    #pragma unroll
    for (int k=0;k<10;k++){ m0[k]=a[k]; m3[k]=d[k]; }
    #pragma unroll
    for (int k=0;k<20;k++){ m1[k]=b1[k]; m2[k]=c[k]; }
  }

  // PRESS_POINT: interior node (512,512) p=0 in the NEW field only
  {
    const int c = 513 - x0;                  // patch col of interior col 512
    if ((unsigned)c < 4u){
      if (jm==512) nA[3*c+2]=0.f;
      if (j0==512) nB[3*c+2]=0.f;
      if (j1==512) nC_[3*c+2]=0.f;
      if (jp==512) nD[3*c+2]=0.f;
    }
  }

  const Ctr  c0 = mkCtr(nB,  qB,  m1);       // center row j0
  const Ctr  c1 = mkCtr(nC_, qC2, m2);       // center row j1
  const Face fS = mkFace(nA, qA, m0);        // S face of row j0
  const Face fN = mkFace(nD, qD, m3);        // N face of row j1

  const int o0 = j0*NXC + x0;
  // output row j0: S = fS, N = c1's center face
  emitRow(nA,nB,nC_, qB,
          qA[0],qA[1],qA[3],qA[4],           // old S (row jm, cols 1,2)
          qC2[3],qC2[4],qC2[6],qC2[7],       // old N (row j1, patch cols 1,2)
          c0, fS, c1.f,
          cc,uc,convc,pc,dc,relax,rdt, o0, out);
  // output row j1: S = c0's center face, N = fN
  emitRow(nB,nC_,nD, qC2,
          qB[3],qB[4],qB[6],qB[7],           // old S (row j0, patch cols 1,2)
          qD[0],qD[1],qD[3],qD[4],           // old N (row jp, cols 1,2)
          c1, c0.f, fN,
          cc,uc,convc,pc,dc,relax,rdt, o0+NXC, out);
}

extern "C" void kernel_launch(void* const* d_in, const int* in_sizes, int n_in,
                              void* d_out, int out_size, void* d_ws, size_t ws_size,
                              hipStream_t stream) {
  const float* uvp = (const float*)d_in[0];   // original_uv
  const float* uvo = (const float*)d_in[1];   // uv_old
  const float* ndy = (const float*)d_in[2];   // node_y
  const float* ebm = (const float*)d_in[4];   // extended_block_metrics
  const float* dtg = (const float*)d_in[5];   // dt_graph
  const float* th  = (const float*)d_in[6];   // pde_theta
  const float* rl  = (const float*)d_in[7];   // relaxtion
  float* out = (float*)d_out;

  // 24 edge blocks first (overlap main wave-front) + 8x128 fast tiles
  fd_kernel<<<dim3(NEDGE_BLK + 1024), dim3(256), 0, stream>>>(uvp, uvo, ndy, ebm, dtg, th, rl, out);
}

// Round 6
// 182.787 us; speedup vs baseline: 1.0094x; 1.0094x over previous
//
#include <hip/hip_runtime.h>

// FD_discretizer on fixed 1024x1024 grid, Ex=Ey=1026 extended grid.
// Round 6: = round 5 structure (2x2 outputs/thread, 8x128 tile, XCD column
// affinity) with two fixes:
//  - normal stores (round 5's nontemporal stores doubled WRITE_SIZE: partial
//    64B lines bypass L2 write-combining)
//  - __launch_bounds__(256,1): let the allocator keep all ~144 loaded floats
//    live (~200+ VGPR) so loads issue in ONE up-front batch -> one latency
//    exposure per wave instead of ~10 vmcnt-sequenced batches at 96 VGPR.

#define NXC 1024               // NX == NY
#define EXC 1026               // Ex == Ey
#define NN  (NXC*NXC)

enum { T_NORMAL=0, T_INFLOW=4, T_OUTFLOW=5, T_WALL=6, T_PRESS=7 };

struct V3 { float u,v,p; };

__device__ __forceinline__ int ntype(int io,int jo){
  if (io==NXC-1) return T_OUTFLOW;
  if (io==0)     return T_INFLOW;
  if (jo==0 || jo==NXC-1) return T_WALL;
  return T_NORMAL;
}

// BC-enforced extended field value at extended coords (je,ie) in [0,1025]^2.
template<bool NEWF>
__device__ __forceinline__ V3 ext_at(int je,int ie,
    const float* __restrict__ uvp,
    const float* __restrict__ node_y)
{
  V3 r;
  const bool bl=(ie==0), br=(ie==EXC-1), bb=(je==0), bt=(je==EXC-1);
  const bool onx = bl||br, ony = bb||bt;
  const bool ghost = (onx && !ony) || (ony && !onx);   // ring minus corners
  if (!ghost){
    int io = ie-1; io = io<0?0:(io>NXC-1?NXC-1:io);
    int jo = je-1; jo = jo<0?0:(jo>NXC-1?NXC-1:jo);
    int m3 = 3*(jo*NXC+io);
    r.u = uvp[m3]; r.v = uvp[m3+1]; r.p = uvp[m3+2];
    if (NEWF && je==EXC/2 && ie==EXC/2) r.p = 0.f;     // PRESS_POINT
    return r;
  }
  int dje=0, die=0, gt;
  if (bl)      { die= 1; gt=T_INFLOW;  }
  else if (br) { die=-1; gt=T_OUTFLOW; }
  else if (bb) { dje= 1; gt=T_WALL;    }
  else         { dje=-1; gt=T_WALL;    }
  int io1 = ie+die-1, jo1 = je+dje-1;
  int m1 = 3*(jo1*NXC+io1);
  int m2 = 3*((jo1+dje)*NXC + (io1+die));
  float u2=uvp[m2], v2=uvp[m2+1], p2=uvp[m2+2];
  int nt1 = ntype(io1,jo1);
  if (gt==T_OUTFLOW){
    float p1 = (nt1==T_OUTFLOW) ? 0.f : uvp[m1+2];
    r.u=u2; r.v=v2; r.p = 2.f*p1 - p2;
  } else {
    float du,dv;
    if (nt1==T_INFLOW || nt1==T_WALL){ du=node_y[m1]; dv=node_y[m1+1]; }
    else                             { du=uvp[m1];    dv=uvp[m1+1];    }
    r.u = 2.f*du - u2; r.v = 2.f*dv - v2; r.p = p2;
  }
  return r;
}

// full slow-path computation for one output node (round-2-verified)
__device__ void process_slow(int io,int jo,
    const float* __restrict__ uvp, const float* __restrict__ uvo,
    const float* __restrict__ ndy, const float* __restrict__ ebm,
    float dt,float uc,float cc,float convc,float pc,float dc,float relax,
    float* __restrict__ out)
{
  const int o = jo*NXC + io;
  const int ie0 = io+1, je0 = jo+1;
  V3 C  = ext_at<true >(je0,  ie0,  uvp, ndy);
  V3 W  = ext_at<true >(je0,  ie0-1,uvp, ndy);
  V3 E  = ext_at<true >(je0,  ie0+1,uvp, ndy);
  V3 S  = ext_at<true >(je0-1,ie0,  uvp, ndy);
  V3 Nn = ext_at<true >(je0+1,ie0,  uvp, ndy);
  V3 SW = ext_at<true >(je0-1,ie0-1,uvp, ndy);
  V3 SE = ext_at<true >(je0-1,ie0+1,uvp, ndy);
  V3 NW = ext_at<true >(je0+1,ie0-1,uvp, ndy);
  V3 NE = ext_at<true >(je0+1,ie0+1,uvp, ndy);
  V3 Co = ext_at<false>(je0,  ie0,  uvo, ndy);
  V3 Wo = ext_at<false>(je0,  ie0-1,uvo, ndy);
  V3 Eo = ext_at<false>(je0,  ie0+1,uvo, ndy);
  V3 So = ext_at<false>(je0-1,ie0,  uvo, ndy);
  V3 No = ext_at<false>(je0+1,ie0,  uvo, ndy);

  const int eC = je0*EXC+ie0;
  const int eW = eC-1, eE = eC+1, eS = eC-EXC, eN = eC+EXC;
  float dxxC=ebm[5*eC+0], dxyC=ebm[5*eC+1], dexC=ebm[5*eC+2],
        deyC=ebm[5*eC+3], JmC=ebm[5*eC+4];
  float dxxW=ebm[5*eW+0], dxyW=ebm[5*eW+1], JmW=ebm[5*eW+4];
  float dxxE=ebm[5*eE+0], dxyE=ebm[5*eE+1], JmE=ebm[5*eE+4];
  float dexS=ebm[5*eS+2], deyS=ebm[5*eS+3], JmS=ebm[5*eS+4];
  float dexN=ebm[5*eN+2], deyN=ebm[5*eN+3], JmN=ebm[5*eN+4];
  const float rC=1.f/JmC, rW=1.f/JmW, rE=1.f/JmE, rS=1.f/JmS, rN=1.f/JmN;

  float UC=(C.u*dxxC + C.v*dxyC)*rC, UW=(W.u*dxxW + W.v*dxyW)*rW, UE=(E.u*dxxE + E.v*dxyE)*rE;
  float VC=(C.u*dexC + C.v*deyC)*rC, VS=(S.u*dexS + S.v*deyS)*rS, VN=(Nn.u*dexN + Nn.v*deyN)*rN;
  float UCo=(Co.u*dxxC + Co.v*dxyC)*rC, UWo=(Wo.u*dxxW + Wo.v*dxyW)*rW, UEo=(Eo.u*dxxE + Eo.v*dxyE)*rE;
  float VCo=(Co.u*dexC + Co.v*deyC)*rC, VSo=(So.u*dexS + So.v*deyS)*rS, VNo=(No.u*dexN + No.v*deyN)*rN;

  float Ufl =0.5f*(UW +UC ), Ufr =0.5f*(UC +UE );
  float Vfd =0.5f*(VS +VC ), Vfu =0.5f*(VC +VN );
  float Uflo=0.5f*(UWo+UCo), Ufro=0.5f*(UCo+UEo);
  float Vfdo=0.5f*(VSo+VCo), Vfuo=0.5f*(VCo+VNo);

  const float loss = (Ufr - Ufl + Vfu - Vfd) * cc;

  float cnu = 0.5f*(C.u+E.u)*Ufr - 0.5f*(W.u+C.u)*Ufl + 0.5f*(C.u+Nn.u)*Vfu - 0.5f*(S.u+C.u)*Vfd;
  float cnv = 0.5f*(C.v+E.v)*Ufr - 0.5f*(W.v+C.v)*Ufl + 0.5f*(C.v+Nn.v)*Vfu - 0.5f*(S.v+C.v)*Vfd;
  float cou = 0.5f*(Co.u+Eo.u)*Ufro - 0.5f*(Wo.u+Co.u)*Uflo + 0.5f*(Co.u+No.u)*Vfuo - 0.5f*(So.u+Co.u)*Vfdo;
  float cov = 0.5f*(Co.v+Eo.v)*Ufro - 0.5f*(Wo.v+Co.v)*Uflo + 0.5f*(Co.v+No.v)*Vfuo - 0.5f*(So.v+Co.v)*Vfdo;
  const float convu = relax*cou + (1.f-relax)*cnu;
  const float convv = relax*cov + (1.f-relax)*cnv;

  float a11C=(dxxC*dxxC+dxyC*dxyC)*rC, a11W=(dxxW*dxxW+dxyW*dxyW)*rW, a11E=(dxxE*dxxE+dxyE*dxyE)*rE;
  float a22C=(dexC*dexC+deyC*deyC)*rC, a22S=(dexS*dexS+deyS*deyS)*rS, a22N=(dexN*dexN+deyN*deyN)*rN;
  float du = 0.5f*(a11C+a11E)*(E.u -C.u) - 0.5f*(a11W+a11C)*(C.u-W.u)
           + 0.5f*(a22C+a22N)*(Nn.u-C.u) - 0.5f*(a22S+a22C)*(C.u-S.u);
  float dv = 0.5f*(a11C+a11E)*(E.v -C.v) - 0.5f*(a11W+a11C)*(C.v-W.v)
           + 0.5f*(a22C+a22N)*(Nn.v-C.v) - 0.5f*(a22S+a22C)*(C.v-S.v);

  float pqW=W.p*rW, pqE=E.p*rE, pqS=S.p*rS, pqN=Nn.p*rN;
  const float gPx = 0.5f*(pqE*dxxE - pqW*dxxW) + 0.5f*(pqN*dexN - pqS*dexS);
  const float gPy = 0.5f*(pqN*deyN - pqS*deyS) + 0.5f*(pqE*dxyE - pqW*dxyW);

  const float rdt = 1.f/dt;
  const float unst_u = (C.u - Co.u)*rdt*rC;
  const float unst_v = (C.v - Co.v)*rdt*rC;

  const float momu = uc*unst_u + convc*convu + pc*gPx - dc*du;
  const float momv = uc*unst_v + convc*convv + pc*gPy - dc*dv;

  const float visu = (SW.u+SE.u+NW.u+NE.u + 2.f*(S.u+W.u+E.u+Nn.u) + 4.f*C.u)*0.0625f;
  const float visv = (SW.v+SE.v+NW.v+NE.v + 2.f*(S.v+W.v+E.v+Nn.v) + 4.f*C.v)*0.0625f;
  const float visp = (SW.p+SE.p+NW.p+NE.p + 2.f*(S.p+W.p+E.p+Nn.p) + 4.f*C.p)*0.0625f;

  out[o]        = loss;
  out[NN + o]   = momu;
  out[2*NN + o] = momv;
  const int vb = 3*NN + 3*o;
  out[vb]   = visu;
  out[vb+1] = visv;
  out[vb+2] = visp;
}

// ---- fast-path helpers ------------------------------------------------------

struct Face { float V[2],Vo[2],a22[2],pex[2],pey[2]; };
struct Ctr  { float U[4],Uo[4],a11[4],pqx[4],pqy[4],rJc[2]; Face f; };

// center row: n,q = 12 floats (patch cols 0..3), m = 20 floats (metrics cols 0..3)
__device__ __forceinline__ Ctr mkCtr(const float* __restrict__ n,
                                     const float* __restrict__ q,
                                     const float* __restrict__ m){
  Ctr c; float rJ[4];
  #pragma unroll
  for(int k=0;k<4;k++){
    const float dxx=m[5*k], dxy=m[5*k+1];
    rJ[k]=1.f/m[5*k+4];
    c.U[k] =(n[3*k]*dxx + n[3*k+1]*dxy)*rJ[k];
    c.Uo[k]=(q[3*k]*dxx + q[3*k+1]*dxy)*rJ[k];
    c.a11[k]=(dxx*dxx+dxy*dxy)*rJ[k];
    const float pq=n[3*k+2]*rJ[k];
    c.pqx[k]=pq*dxx; c.pqy[k]=pq*dxy;
  }
  #pragma unroll
  for(int i=0;i<2;i++){
    const int k=1+i;
    const float dex=m[5*k+2], dey=m[5*k+3];
    c.rJc[i]=rJ[k];
    c.f.V[i] =(n[3*k]*dex + n[3*k+1]*dey)*rJ[k];
    c.f.Vo[i]=(q[3*k]*dex + q[3*k+1]*dey)*rJ[k];
    c.f.a22[i]=(dex*dex+dey*dey)*rJ[k];
    const float pq=n[3*k+2]*rJ[k];
    c.f.pex[i]=pq*dex; c.f.pey[i]=pq*dey;
  }
  return c;
}

// S/N face row: n = 12 floats (patch cols 0..3), q = 6 floats (cols 1..2),
// m = 10 floats (metric cols 1..2)
__device__ __forceinline__ Face mkFace(const float* __restrict__ n,
                                       const float* __restrict__ q,
                                       const float* __restrict__ m){
  Face f;
  #pragma unroll
  for(int i=0;i<2;i++){
    const float dex=m[5*i+2], dey=m[5*i+3], r=1.f/m[5*i+4];
    const int mm=1+i;
    f.V[i] =(n[3*mm]*dex + n[3*mm+1]*dey)*r;
    f.Vo[i]=(q[3*i]*dex + q[3*i+1]*dey)*r;
    f.a22[i]=(dex*dex+dey*dey)*r;
    const float pq=n[3*mm+2]*r;
    f.pex[i]=pq*dex; f.pey[i]=pq*dey;
  }
  return f;
}

__device__ __forceinline__ void emitRow(
  const float* __restrict__ nS,const float* __restrict__ nC,const float* __restrict__ nN,
  const float* __restrict__ qC,
  float uoS0,float voS0,float uoS1,float voS1,
  float uoN0,float voN0,float uoN1,float voN1,
  const Ctr& ct, const Face& fS, const Face& fN,
  float cc,float uc,float convc,float pc,float dc,float relax,float rdt,
  int o, float* __restrict__ out)
{
  float Lo[2],Mu[2],Mv[2],Vu[2],Vv[2],Vp[2];
  #pragma unroll
  for(int i=0;i<2;i++){
    const int m=1+i;
    const float Ufl =0.5f*(ct.U[m-1]+ct.U[m]),   Ufr =0.5f*(ct.U[m]+ct.U[m+1]);
    const float Uflo=0.5f*(ct.Uo[m-1]+ct.Uo[m]), Ufro=0.5f*(ct.Uo[m]+ct.Uo[m+1]);
    const float Vfd =0.5f*(fS.V[i]+ct.f.V[i]),   Vfu =0.5f*(ct.f.V[i]+fN.V[i]);
    const float Vfdo=0.5f*(fS.Vo[i]+ct.f.Vo[i]), Vfuo=0.5f*(ct.f.Vo[i]+fN.Vo[i]);

    Lo[i]=(Ufr-Ufl+Vfu-Vfd)*cc;

    const float u_c=nC[3*m],   v_c=nC[3*m+1];
    const float uW =nC[3*m-3], vW =nC[3*m-2];
    const float uE =nC[3*m+3], vE =nC[3*m+4];
    const float uS =nS[3*m],   vS =nS[3*m+1];
    const float uN =nN[3*m],   vN =nN[3*m+1];

    const float cnu=0.5f*(u_c+uE)*Ufr-0.5f*(uW+u_c)*Ufl+0.5f*(u_c+uN)*Vfu-0.5f*(uS+u_c)*Vfd;
    const float cnv=0.5f*(v_c+vE)*Ufr-0.5f*(vW+v_c)*Ufl+0.5f*(v_c+vN)*Vfu-0.5f*(vS+v_c)*Vfd;

    const float uoc=qC[3*m],   voc=qC[3*m+1];
    const float uoW=qC[3*m-3], voW=qC[3*m-2];
    const float uoE=qC[3*m+3], voE=qC[3*m+4];
    const float uoS=i?uoS1:uoS0, voS=i?voS1:voS0;
    const float uoN=i?uoN1:uoN0, voN=i?voN1:voN0;

    const float cou=0.5f*(uoc+uoE)*Ufro-0.5f*(uoW+uoc)*Uflo+0.5f*(uoc+uoN)*Vfuo-0.5f*(uoS+uoc)*Vfdo;
    const float cov=0.5f*(voc+voE)*Ufro-0.5f*(voW+voc)*Uflo+0.5f*(voc+voN)*Vfuo-0.5f*(voS+voc)*Vfdo;

    const float convu=relax*cou+(1.f-relax)*cnu;
    const float convv=relax*cov+(1.f-relax)*cnv;

    const float du=0.5f*(ct.a11[m]+ct.a11[m+1])*(uE-u_c)-0.5f*(ct.a11[m-1]+ct.a11[m])*(u_c-uW)
                  +0.5f*(ct.f.a22[i]+fN.a22[i])*(uN-u_c)-0.5f*(fS.a22[i]+ct.f.a22[i])*(u_c-uS);
    const float dv=0.5f*(ct.a11[m]+ct.a11[m+1])*(vE-v_c)-0.5f*(ct.a11[m-1]+ct.a11[m])*(v_c-vW)
                  +0.5f*(ct.f.a22[i]+fN.a22[i])*(vN-v_c)-0.5f*(fS.a22[i]+ct.f.a22[i])*(v_c-vS);

    const float gPx=0.5f*(ct.pqx[m+1]-ct.pqx[m-1])+0.5f*(fN.pex[i]-fS.pex[i]);
    const float gPy=0.5f*(fN.pey[i]-fS.pey[i])+0.5f*(ct.pqy[m+1]-ct.pqy[m-1]);

    const float unst_u=(u_c-uoc)*rdt*ct.rJc[i];
    const float unst_v=(v_c-voc)*rdt*ct.rJc[i];

    Mu[i]=uc*unst_u+convc*convu+pc*gPx-dc*du;
    Mv[i]=uc*unst_v+convc*convv+pc*gPy-dc*dv;

    Vu[i]=(nS[3*m-3]+2.f*nS[3*m]+nS[3*m+3]
      +2.f*(nC[3*m-3]+2.f*nC[3*m]+nC[3*m+3])
          + nN[3*m-3]+2.f*nN[3*m]+nN[3*m+3])*0.0625f;
    Vv[i]=(nS[3*m-2]+2.f*nS[3*m+1]+nS[3*m+4]
      +2.f*(nC[3*m-2]+2.f*nC[3*m+1]+nC[3*m+4])
          + nN[3*m-2]+2.f*nN[3*m+1]+nN[3*m+4])*0.0625f;
    Vp[i]=(nS[3*m-1]+2.f*nS[3*m+2]+nS[3*m+5]
      +2.f*(nC[3*m-1]+2.f*nC[3*m+2]+nC[3*m+5])
          + nN[3*m-1]+2.f*nN[3*m+2]+nN[3*m+5])*0.0625f;
  }
  out[o]        = Lo[0]; out[o+1]        = Lo[1];
  out[NN+o]     = Mu[0]; out[NN+o+1]     = Mu[1];
  out[2*NN+o]   = Mv[0]; out[2*NN+o+1]   = Mv[1];
  const int vb=3*NN+3*o;
  out[vb]   = Vu[0]; out[vb+1] = Vv[0]; out[vb+2] = Vp[0];
  out[vb+3] = Vu[1]; out[vb+4] = Vv[1]; out[vb+5] = Vp[1];
}

#define NEDGE_BLK 24

extern "C" __global__ void __launch_bounds__(256, 1)
fd_kernel(const float* __restrict__ uvp,     // original_uv  n x 3
          const float* __restrict__ uvo,     // uv_old       n x 3
          const float* __restrict__ ndy,     // node_y       n x 3
          const float* __restrict__ ebm,     // ext metrics  n_ext x 5
          const float* __restrict__ dtg,     // dt           1
          const float* __restrict__ th,      // pde_theta    5
          const float* __restrict__ rl,      // relaxation   1
          float* __restrict__ out)
{
  const int bid = blockIdx.x;
  const int tid = threadIdx.x;

  const float dt   = dtg[0];
  const float uc   = th[0], cc = th[1], convc = th[2], pc = th[3], dc = th[4];
  const float relax= rl[0];
  const float rdt  = 1.f/dt;

  if (bid < NEDGE_BLK){
    // boundary frame: jo in {0,1023} all io, plus io in {0,1,1022,1023}
    // for jo in [1,1022]. 6136 nodes, 1 node/thread.
    const int t = bid*256 + tid;
    if (t >= 6136) return;
    int io, jo;
    if (t < 2048){ jo = (t < 1024) ? 0 : 1023; io = t & 1023; }
    else { int u = t - 2048; jo = 1 + (u >> 2); int c = u & 3; io = (c < 2) ? c : 1020 + c; }
    process_slow(io, jo, uvp,uvo,ndy,ebm, dt,uc,cc,convc,pc,dc,relax, out);
    return;
  }

  // -------- fast path: 2x2 outputs/thread; tile = 8 rows x 128 cols --------
  const int b  = bid - NEDGE_BLK;
  const int ct_ = b & 7, rt = b >> 3;        // ct_ -> fixed XCD column strip
  const int tx = tid & 63, ty = tid >> 6;
  const int x0 = 2 + ct_*128 + 2*tx;         // output cols x0, x0+1
  if (x0 > 1020) return;
  int jo0 = 1 + rt*8 + ty*2;                 // output rows jo0, jo0+1
  if (jo0 > 1021) jo0 = 1021;                // clamp: duplicate-write same values

  const int jm=jo0-1, j0=jo0, j1=jo0+1, jp=jo0+2;

  // new field: 4 rows x patch cols 0..3 (interior cols x0-1 .. x0+2)
  float nA[12], nB[12], nC_[12], nD[12];
  {
    const float* a = uvp + 3*(jm*NXC + x0-1);
    const float* b1= uvp + 3*(j0*NXC + x0-1);
    const float* c = uvp + 3*(j1*NXC + x0-1);
    const float* d = uvp + 3*(jp*NXC + x0-1);
    #pragma unroll
    for (int k=0;k<12;k++){ nA[k]=a[k]; nB[k]=b1[k]; nC_[k]=c[k]; nD[k]=d[k]; }
  }
  // old field: outer rows only cols x0..x0+1
  float qA[6], qB[12], qC2[12], qD[6];
  {
    const float* a = uvo + 3*(jm*NXC + x0);
    const float* b1= uvo + 3*(j0*NXC + x0-1);
    const float* c = uvo + 3*(j1*NXC + x0-1);
    const float* d = uvo + 3*(jp*NXC + x0);
    #pragma unroll
    for (int k=0;k<6;k++){ qA[k]=a[k]; qD[k]=d[k]; }
    #pragma unroll
    for (int k=0;k<12;k++){ qB[k]=b1[k]; qC2[k]=c[k]; }
  }
  // metrics: ext rows jo0..jo0+3; S/N rows only metric cols 1..2
  float m0[10], m1[20], m2[20], m3[10];
  {
    const float* a = ebm + 5*((jo0  )*EXC + x0+1);
    const float* b1= ebm + 5*((jo0+1)*EXC + x0);
    const float* c = ebm + 5*((jo0+2)*EXC + x0);
    const float* d = ebm + 5*((jo0+3)*EXC + x0+1);
    #pragma unroll
    for (int k=0;k<10;k++){ m0[k]=a[k]; m3[k]=d[k]; }
    #pragma unroll
    for (int k=0;k<20;k++){ m1[k]=b1[k]; m2[k]=c[k]; }
  }

  // PRESS_POINT: interior node (512,512) p=0 in the NEW field only
  {
    const int c = 513 - x0;                  // patch col of interior col 512
    if ((unsigned)c < 4u){
      if (jm==512) nA[3*c+2]=0.f;
      if (j0==512) nB[3*c+2]=0.f;
      if (j1==512) nC_[3*c+2]=0.f;
      if (jp==512) nD[3*c+2]=0.f;
    }
  }

  const Ctr  c0 = mkCtr(nB,  qB,  m1);       // center row j0
  const Ctr  c1 = mkCtr(nC_, qC2, m2);       // center row j1
  const Face fS = mkFace(nA, qA, m0);        // S face of row j0
  const Face fN = mkFace(nD, qD, m3);        // N face of row j1

  const int o0 = j0*NXC + x0;
  // output row j0: S = fS, N = c1's center face
  emitRow(nA,nB,nC_, qB,
          qA[0],qA[1],qA[3],qA[4],           // old S (row jm, cols 1,2)
          qC2[3],qC2[4],qC2[6],qC2[7],       // old N (row j1, patch cols 1,2)
          c0, fS, c1.f,
          cc,uc,convc,pc,dc,relax,rdt, o0, out);
  // output row j1: S = c0's center face, N = fN
  emitRow(nB,nC_,nD, qC2,
          qB[3],qB[4],qB[6],qB[7],           // old S (row j0, patch cols 1,2)
          qD[0],qD[1],qD[3],qD[4],           // old N (row jp, cols 1,2)
          c1, c0.f, fN,
          cc,uc,convc,pc,dc,relax,rdt, o0+NXC, out);
}

extern "C" void kernel_launch(void* const* d_in, const int* in_sizes, int n_in,
                              void* d_out, int out_size, void* d_ws, size_t ws_size,
                              hipStream_t stream) {
  const float* uvp = (const float*)d_in[0];   // original_uv
  const float* uvo = (const float*)d_in[1];   // uv_old
  const float* ndy = (const float*)d_in[2];   // node_y
  const float* ebm = (const float*)d_in[4];   // extended_block_metrics
  const float* dtg = (const float*)d_in[5];   // dt_graph
  const float* th  = (const float*)d_in[6];   // pde_theta
  const float* rl  = (const float*)d_in[7];   // relaxtion
  float* out = (float*)d_out;

  // 24 edge blocks first (overlap main wave-front) + 8x128 fast tiles
  fd_kernel<<<dim3(NEDGE_BLK + 1024), dim3(256), 0, stream>>>(uvp, uvo, ndy, ebm, dtg, th, rl, out);
}

// Round 7
// 181.000 us; speedup vs baseline: 1.0194x; 1.0099x over previous
//
#include <hip/hip_runtime.h>

// FD_discretizer on fixed 1024x1024 grid, Ex=Ey=1026 extended grid.
// Round 7: LDS-staged stencil. Each fast block stages a 10x66 halo tile:
// phase 1 computes per-node derived quantities ONCE (U,V,Uo,Vo,a11,a22,
// pq*metrics,1/J) into SoA LDS planes (conflict-free), phase 2 computes an
// 8x64 output tile (2 outputs/thread) purely from LDS. One latency exposure
// per phase instead of ~10 vmcnt-batched exposures per wave (R2-R6 plateau).
// Edge frame handled by 24 dedicated slow blocks placed first.

#define NXC 1024               // NX == NY
#define EXC 1026               // Ex == Ey
#define NN  (NXC*NXC)

#define TB_ROWS 8
#define TB_COLS 64
#define H_ROWS  10             // TB_ROWS + 2
#define H_COLS  66             // TB_COLS + 2
#define NNODE   (H_ROWS*H_COLS)   // 660

enum { T_NORMAL=0, T_INFLOW=4, T_OUTFLOW=5, T_WALL=6, T_PRESS=7 };

struct V3 { float u,v,p; };

__device__ __forceinline__ int ntype(int io,int jo){
  if (io==NXC-1) return T_OUTFLOW;
  if (io==0)     return T_INFLOW;
  if (jo==0 || jo==NXC-1) return T_WALL;
  return T_NORMAL;
}

// BC-enforced extended field value at extended coords (je,ie) in [0,1025]^2.
template<bool NEWF>
__device__ __forceinline__ V3 ext_at(int je,int ie,
    const float* __restrict__ uvp,
    const float* __restrict__ node_y)
{
  V3 r;
  const bool bl=(ie==0), br=(ie==EXC-1), bb=(je==0), bt=(je==EXC-1);
  const bool onx = bl||br, ony = bb||bt;
  const bool ghost = (onx && !ony) || (ony && !onx);   // ring minus corners
  if (!ghost){
    int io = ie-1; io = io<0?0:(io>NXC-1?NXC-1:io);
    int jo = je-1; jo = jo<0?0:(jo>NXC-1?NXC-1:jo);
    int m3 = 3*(jo*NXC+io);
    r.u = uvp[m3]; r.v = uvp[m3+1]; r.p = uvp[m3+2];
    if (NEWF && je==EXC/2 && ie==EXC/2) r.p = 0.f;     // PRESS_POINT
    return r;
  }
  int dje=0, die=0, gt;
  if (bl)      { die= 1; gt=T_INFLOW;  }
  else if (br) { die=-1; gt=T_OUTFLOW; }
  else if (bb) { dje= 1; gt=T_WALL;    }
  else         { dje=-1; gt=T_WALL;    }
  int io1 = ie+die-1, jo1 = je+dje-1;
  int m1 = 3*(jo1*NXC+io1);
  int m2 = 3*((jo1+dje)*NXC + (io1+die));
  float u2=uvp[m2], v2=uvp[m2+1], p2=uvp[m2+2];
  int nt1 = ntype(io1,jo1);
  if (gt==T_OUTFLOW){
    float p1 = (nt1==T_OUTFLOW) ? 0.f : uvp[m1+2];
    r.u=u2; r.v=v2; r.p = 2.f*p1 - p2;
  } else {
    float du,dv;
    if (nt1==T_INFLOW || nt1==T_WALL){ du=node_y[m1]; dv=node_y[m1+1]; }
    else                             { du=uvp[m1];    dv=uvp[m1+1];    }
    r.u = 2.f*du - u2; r.v = 2.f*dv - v2; r.p = p2;
  }
  return r;
}

// full slow-path computation for one output node (round-2-verified)
__device__ void process_slow(int io,int jo,
    const float* __restrict__ uvp, const float* __restrict__ uvo,
    const float* __restrict__ ndy, const float* __restrict__ ebm,
    float dt,float uc,float cc,float convc,float pc,float dc,float relax,
    float* __restrict__ out)
{
  const int o = jo*NXC + io;
  const int ie0 = io+1, je0 = jo+1;
  V3 C  = ext_at<true >(je0,  ie0,  uvp, ndy);
  V3 W  = ext_at<true >(je0,  ie0-1,uvp, ndy);
  V3 E  = ext_at<true >(je0,  ie0+1,uvp, ndy);
  V3 S  = ext_at<true >(je0-1,ie0,  uvp, ndy);
  V3 Nn = ext_at<true >(je0+1,ie0,  uvp, ndy);
  V3 SW = ext_at<true >(je0-1,ie0-1,uvp, ndy);
  V3 SE = ext_at<true >(je0-1,ie0+1,uvp, ndy);
  V3 NW = ext_at<true >(je0+1,ie0-1,uvp, ndy);
  V3 NE = ext_at<true >(je0+1,ie0+1,uvp, ndy);
  V3 Co = ext_at<false>(je0,  ie0,  uvo, ndy);
  V3 Wo = ext_at<false>(je0,  ie0-1,uvo, ndy);
  V3 Eo = ext_at<false>(je0,  ie0+1,uvo, ndy);
  V3 So = ext_at<false>(je0-1,ie0,  uvo, ndy);
  V3 No = ext_at<false>(je0+1,ie0,  uvo, ndy);

  const int eC = je0*EXC+ie0;
  const int eW = eC-1, eE = eC+1, eS = eC-EXC, eN = eC+EXC;
  float dxxC=ebm[5*eC+0], dxyC=ebm[5*eC+1], dexC=ebm[5*eC+2],
        deyC=ebm[5*eC+3], JmC=ebm[5*eC+4];
  float dxxW=ebm[5*eW+0], dxyW=ebm[5*eW+1], JmW=ebm[5*eW+4];
  float dxxE=ebm[5*eE+0], dxyE=ebm[5*eE+1], JmE=ebm[5*eE+4];
  float dexS=ebm[5*eS+2], deyS=ebm[5*eS+3], JmS=ebm[5*eS+4];
  float dexN=ebm[5*eN+2], deyN=ebm[5*eN+3], JmN=ebm[5*eN+4];
  const float rC=1.f/JmC, rW=1.f/JmW, rE=1.f/JmE, rS=1.f/JmS, rN=1.f/JmN;

  float UC=(C.u*dxxC + C.v*dxyC)*rC, UW=(W.u*dxxW + W.v*dxyW)*rW, UE=(E.u*dxxE + E.v*dxyE)*rE;
  float VC=(C.u*dexC + C.v*deyC)*rC, VS=(S.u*dexS + S.v*deyS)*rS, VN=(Nn.u*dexN + Nn.v*deyN)*rN;
  float UCo=(Co.u*dxxC + Co.v*dxyC)*rC, UWo=(Wo.u*dxxW + Wo.v*dxyW)*rW, UEo=(Eo.u*dxxE + Eo.v*dxyE)*rE;
  float VCo=(Co.u*dexC + Co.v*deyC)*rC, VSo=(So.u*dexS + So.v*deyS)*rS, VNo=(No.u*dexN + No.v*deyN)*rN;

  float Ufl =0.5f*(UW +UC ), Ufr =0.5f*(UC +UE );
  float Vfd =0.5f*(VS +VC ), Vfu =0.5f*(VC +VN );
  float Uflo=0.5f*(UWo+UCo), Ufro=0.5f*(UCo+UEo);
  float Vfdo=0.5f*(VSo+VCo), Vfuo=0.5f*(VCo+VNo);

  const float loss = (Ufr - Ufl + Vfu - Vfd) * cc;

  float cnu = 0.5f*(C.u+E.u)*Ufr - 0.5f*(W.u+C.u)*Ufl + 0.5f*(C.u+Nn.u)*Vfu - 0.5f*(S.u+C.u)*Vfd;
  float cnv = 0.5f*(C.v+E.v)*Ufr - 0.5f*(W.v+C.v)*Ufl + 0.5f*(C.v+Nn.v)*Vfu - 0.5f*(S.v+C.v)*Vfd;
  float cou = 0.5f*(Co.u+Eo.u)*Ufro - 0.5f*(Wo.u+Co.u)*Uflo + 0.5f*(Co.u+No.u)*Vfuo - 0.5f*(So.u+Co.u)*Vfdo;
  float cov = 0.5f*(Co.v+Eo.v)*Ufro - 0.5f*(Wo.v+Co.v)*Uflo + 0.5f*(Co.v+No.v)*Vfuo - 0.5f*(So.v+Co.v)*Vfdo;
  const float convu = relax*cou + (1.f-relax)*cnu;
  const float convv = relax*cov + (1.f-relax)*cnv;

  float a11C=(dxxC*dxxC+dxyC*dxyC)*rC, a11W=(dxxW*dxxW+dxyW*dxyW)*rW, a11E=(dxxE*dxxE+dxyE*dxyE)*rE;
  float a22C=(dexC*dexC+deyC*deyC)*rC, a22S=(dexS*dexS+deyS*deyS)*rS, a22N=(dexN*dexN+deyN*deyN)*rN;
  float du = 0.5f*(a11C+a11E)*(E.u -C.u) - 0.5f*(a11W+a11C)*(C.u-W.u)
           + 0.5f*(a22C+a22N)*(Nn.u-C.u) - 0.5f*(a22S+a22C)*(C.u-S.u);
  float dv = 0.5f*(a11C+a11E)*(E.v -C.v) - 0.5f*(a11W+a11C)*(C.v-W.v)
           + 0.5f*(a22C+a22N)*(Nn.v-C.v) - 0.5f*(a22S+a22C)*(C.v-S.v);

  float pqW=W.p*rW, pqE=E.p*rE, pqS=S.p*rS, pqN=Nn.p*rN;
  const float gPx = 0.5f*(pqE*dxxE - pqW*dxxW) + 0.5f*(pqN*dexN - pqS*dexS);
  const float gPy = 0.5f*(pqN*deyN - pqS*deyS) + 0.5f*(pqE*dxyE - pqW*dxyW);

  const float rdt = 1.f/dt;
  const float unst_u = (C.u - Co.u)*rdt*rC;
  const float unst_v = (C.v - Co.v)*rdt*rC;

  const float momu = uc*unst_u + convc*convu + pc*gPx - dc*du;
  const float momv = uc*unst_v + convc*convv + pc*gPy - dc*dv;

  const float visu = (SW.u+SE.u+NW.u+NE.u + 2.f*(S.u+W.u+E.u+Nn.u) + 4.f*C.u)*0.0625f;
  const float visv = (SW.v+SE.v+NW.v+NE.v + 2.f*(S.v+W.v+E.v+Nn.v) + 4.f*C.v)*0.0625f;
  const float visp = (SW.p+SE.p+NW.p+NE.p + 2.f*(S.p+W.p+E.p+Nn.p) + 4.f*C.p)*0.0625f;

  out[o]        = loss;
  out[NN + o]   = momu;
  out[2*NN + o] = momv;
  const int vb = 3*NN + 3*o;
  out[vb]   = visu;
  out[vb+1] = visv;
  out[vb+2] = visp;
}

#define NEDGE_BLK 24

// LDS plane ids
#define P_U   0
#define P_V   1
#define P_P   2
#define P_UO  3
#define P_VO  4
#define P_CU  5     // contravariant U (new)
#define P_CV  6     // contravariant V (new)
#define P_CUO 7
#define P_CVO 8
#define P_A11 9
#define P_A22 10
#define P_PQX 11
#define P_PQY 12
#define P_PEX 13
#define P_PEY 14
#define P_RJ  15

extern "C" __global__ void __launch_bounds__(256)
fd_kernel(const float* __restrict__ uvp,     // original_uv  n x 3
          const float* __restrict__ uvo,     // uv_old       n x 3
          const float* __restrict__ ndy,     // node_y       n x 3
          const float* __restrict__ ebm,     // ext metrics  n_ext x 5
          const float* __restrict__ dtg,     // dt           1
          const float* __restrict__ th,      // pde_theta    5
          const float* __restrict__ rl,      // relaxation   1
          float* __restrict__ out)
{
  const int bid = blockIdx.x;
  const int tid = threadIdx.x;

  const float dt   = dtg[0];
  const float uc   = th[0], cc = th[1], convc = th[2], pc = th[3], dc = th[4];
  const float relax= rl[0];
  const float rdt  = 1.f/dt;

  if (bid < NEDGE_BLK){
    // boundary frame: jo in {0,1023} all io, plus io in {0,1,1022,1023}
    // for jo in [1,1022]. 6136 nodes, 1 node/thread.
    const int t = bid*256 + tid;
    if (t >= 6136) return;
    int io, jo;
    if (t < 2048){ jo = (t < 1024) ? 0 : 1023; io = t & 1023; }
    else { int u = t - 2048; jo = 1 + (u >> 2); int c = u & 3; io = (c < 2) ? c : 1020 + c; }
    process_slow(io, jo, uvp,uvo,ndy,ebm, dt,uc,cc,convc,pc,dc,relax, out);
    return;
  }

  // ---------------- fast path: LDS-staged 8x64 output tile -----------------
  __shared__ float sm[16][NNODE];            // 16 SoA planes, 42.2 KB

  const int b   = bid - NEDGE_BLK;
  const int ctl = b & 15, rt = b >> 4;       // 16 col tiles x 128 row tiles
  int X0  = 2 + ctl*TB_COLS;  if (X0  > 958)  X0  = 958;   // cols X0..X0+63 in [2,1021]
  int jo0 = 1 + rt*TB_ROWS;   if (jo0 > 1015) jo0 = 1015;  // rows jo0..jo0+7 in [1,1022]

  // ---- phase 1: stage 10x66 halo nodes, derived quantities computed once ----
  #pragma unroll
  for (int it=0; it<3; ++it){
    const int idx = tid + it*256;
    if (idx < NNODE){
      const int r  = idx / H_COLS;
      const int c  = idx - r*H_COLS;
      const int jo = jo0 - 1 + r;            // interior row in [0,1023]
      const int io = X0  - 1 + c;            // interior col in [1,1022]
      const int g3 = 3*(jo*NXC + io);
      float u = uvp[g3], v = uvp[g3+1], p = uvp[g3+2];
      if (jo==512 && io==512) p = 0.f;       // PRESS_POINT (new field only)
      const float uo = uvo[g3], vo = uvo[g3+1];
      const int e5 = 5*((jo+1)*EXC + io + 1);
      const float dxx=ebm[e5], dxy=ebm[e5+1], dex=ebm[e5+2], dey=ebm[e5+3], Jm=ebm[e5+4];
      const float rJ = 1.f/Jm;
      sm[P_U ][idx]=u;  sm[P_V ][idx]=v;  sm[P_P ][idx]=p;
      sm[P_UO][idx]=uo; sm[P_VO][idx]=vo;
      sm[P_CU ][idx]=(u *dxx + v *dxy)*rJ;
      sm[P_CV ][idx]=(u *dex + v *dey)*rJ;
      sm[P_CUO][idx]=(uo*dxx + vo*dxy)*rJ;
      sm[P_CVO][idx]=(uo*dex + vo*dey)*rJ;
      sm[P_A11][idx]=(dxx*dxx + dxy*dxy)*rJ;
      sm[P_A22][idx]=(dex*dex + dey*dey)*rJ;
      const float pq = p*rJ;
      sm[P_PQX][idx]=pq*dxx; sm[P_PQY][idx]=pq*dxy;
      sm[P_PEX][idx]=pq*dex; sm[P_PEY][idx]=pq*dey;
      sm[P_RJ ][idx]=rJ;
    }
  }
  __syncthreads();

  // ---- phase 2: 2 outputs per thread, all reads from LDS ----
  const int tx = tid & 63, ty = tid >> 6;
  #pragma unroll
  for (int kk=0; kk<2; ++kk){
    const int r = 1 + ty*2 + kk;             // local halo row of center
    const int c = 1 + tx;                    // local halo col of center
    const int iC = r*H_COLS + c;
    const int iW = iC-1, iE = iC+1, iS = iC-H_COLS, iN = iC+H_COLS;

    const float UC=sm[P_CU][iC], UW=sm[P_CU][iW], UE=sm[P_CU][iE];
    const float VC=sm[P_CV][iC], VS=sm[P_CV][iS], VN=sm[P_CV][iN];
    const float UCo=sm[P_CUO][iC], UWo=sm[P_CUO][iW], UEo=sm[P_CUO][iE];
    const float VCo=sm[P_CVO][iC], VSo=sm[P_CVO][iS], VNo=sm[P_CVO][iN];

    const float Ufl =0.5f*(UW +UC ), Ufr =0.5f*(UC +UE );
    const float Vfd =0.5f*(VS +VC ), Vfu =0.5f*(VC +VN );
    const float Uflo=0.5f*(UWo+UCo), Ufro=0.5f*(UCo+UEo);
    const float Vfdo=0.5f*(VSo+VCo), Vfuo=0.5f*(VCo+VNo);

    const float loss = (Ufr - Ufl + Vfu - Vfd) * cc;

    const float u_c=sm[P_U][iC], v_c=sm[P_V][iC];
    const float uW =sm[P_U][iW], vW =sm[P_V][iW];
    const float uE =sm[P_U][iE], vE =sm[P_V][iE];
    const float uS =sm[P_U][iS], vS =sm[P_V][iS];
    const float uN =sm[P_U][iN], vN =sm[P_V][iN];

    const float cnu = 0.5f*(u_c+uE)*Ufr - 0.5f*(uW+u_c)*Ufl
                    + 0.5f*(u_c+uN)*Vfu - 0.5f*(uS+u_c)*Vfd;
    const float cnv = 0.5f*(v_c+vE)*Ufr - 0.5f*(vW+v_c)*Ufl
                    + 0.5f*(v_c+vN)*Vfu - 0.5f*(vS+v_c)*Vfd;

    const float uoc=sm[P_UO][iC], voc=sm[P_VO][iC];
    const float uoW=sm[P_UO][iW], voW=sm[P_VO][iW];
    const float uoE=sm[P_UO][iE], voE=sm[P_VO][iE];
    const float uoS=sm[P_UO][iS], voS=sm[P_VO][iS];
    const float uoN=sm[P_UO][iN], voN=sm[P_VO][iN];

    const float cou = 0.5f*(uoc+uoE)*Ufro - 0.5f*(uoW+uoc)*Uflo
                    + 0.5f*(uoc+uoN)*Vfuo - 0.5f*(uoS+uoc)*Vfdo;
    const float cov = 0.5f*(voc+voE)*Ufro - 0.5f*(voW+voc)*Uflo
                    + 0.5f*(voc+voN)*Vfuo - 0.5f*(voS+voc)*Vfdo;

    const float convu = relax*cou + (1.f-relax)*cnu;
    const float convv = relax*cov + (1.f-relax)*cnv;

    const float a11C=sm[P_A11][iC], a11W=sm[P_A11][iW], a11E=sm[P_A11][iE];
    const float a22C=sm[P_A22][iC], a22S=sm[P_A22][iS], a22N=sm[P_A22][iN];
    const float du = 0.5f*(a11C+a11E)*(uE-u_c) - 0.5f*(a11W+a11C)*(u_c-uW)
                   + 0.5f*(a22C+a22N)*(uN-u_c) - 0.5f*(a22S+a22C)*(u_c-uS);
    const float dv = 0.5f*(a11C+a11E)*(vE-v_c) - 0.5f*(a11W+a11C)*(v_c-vW)
                   + 0.5f*(a22C+a22N)*(vN-v_c) - 0.5f*(a22S+a22C)*(v_c-vS);

    const float gPx = 0.5f*(sm[P_PQX][iE]-sm[P_PQX][iW]) + 0.5f*(sm[P_PEX][iN]-sm[P_PEX][iS]);
    const float gPy = 0.5f*(sm[P_PEY][iN]-sm[P_PEY][iS]) + 0.5f*(sm[P_PQY][iE]-sm[P_PQY][iW]);

    const float rJC = sm[P_RJ][iC];
    const float unst_u = (u_c - uoc)*rdt*rJC;
    const float unst_v = (v_c - voc)*rdt*rJC;

    const float momu = uc*unst_u + convc*convu + pc*gPx - dc*du;
    const float momv = uc*unst_v + convc*convv + pc*gPy - dc*dv;

    // vis: [1 2 1; 2 4 2; 1 2 1]/16 over 3x3
    const float uSW=sm[P_U][iS-1], uSE=sm[P_U][iS+1], uNW=sm[P_U][iN-1], uNE=sm[P_U][iN+1];
    const float vSW=sm[P_V][iS-1], vSE=sm[P_V][iS+1], vNW=sm[P_V][iN-1], vNE=sm[P_V][iN+1];
    const float p_c=sm[P_P][iC];
    const float pW=sm[P_P][iW], pE=sm[P_P][iE], pS=sm[P_P][iS], pN=sm[P_P][iN];
    const float pSW=sm[P_P][iS-1], pSE=sm[P_P][iS+1], pNW=sm[P_P][iN-1], pNE=sm[P_P][iN+1];

    const float visu=(uSW+uSE+uNW+uNE + 2.f*(uS+uW+uE+uN) + 4.f*u_c)*0.0625f;
    const float visv=(vSW+vSE+vNW+vNE + 2.f*(vS+vW+vE+vN) + 4.f*v_c)*0.0625f;
    const float visp=(pSW+pSE+pNW+pNE + 2.f*(pS+pW+pE+pN) + 4.f*p_c)*0.0625f;

    const int j = jo0 + ty*2 + kk;
    const int o = j*NXC + X0 + tx;
    out[o]        = loss;
    out[NN + o]   = momu;
    out[2*NN + o] = momv;
    const int vb = 3*NN + 3*o;
    out[vb]   = visu;
    out[vb+1] = visv;
    out[vb+2] = visp;
  }
}

extern "C" void kernel_launch(void* const* d_in, const int* in_sizes, int n_in,
                              void* d_out, int out_size, void* d_ws, size_t ws_size,
                              hipStream_t stream) {
  const float* uvp = (const float*)d_in[0];   // original_uv
  const float* uvo = (const float*)d_in[1];   // uv_old
  const float* ndy = (const float*)d_in[2];   // node_y
  const float* ebm = (const float*)d_in[4];   // extended_block_metrics
  const float* dtg = (const float*)d_in[5];   // dt_graph
  const float* th  = (const float*)d_in[6];   // pde_theta
  const float* rl  = (const float*)d_in[7];   // relaxtion
  float* out = (float*)d_out;

  // 24 edge blocks first (overlap main wave-front) + 16x128 = 2048 fast tiles
  fd_kernel<<<dim3(NEDGE_BLK + 2048), dim3(256), 0, stream>>>(uvp, uvo, ndy, ebm, dtg, th, rl, out);
}